// Round 6
// baseline (604.482 us; speedup 1.0000x reference)
//
#include <hip/hip_runtime.h>
#include <cstddef>
#include <cstdint>

typedef _Float16 f16x8 __attribute__((ext_vector_type(8)));
typedef _Float16 f16x4 __attribute__((ext_vector_type(4)));
typedef float f32x4 __attribute__((ext_vector_type(4)));

static constexpr int BATCH = 8;
static constexpr int TQ = 2048;
static constexpr int TK = 2048;
static constexpr int DIM = 1024;
static constexpr size_t CTX_ELEMS = (size_t)BATCH * TQ * DIM;   // 16,777,216
static constexpr size_t ATT_ELEMS = (size_t)BATCH * TQ * TK;    // 33,554,432

// ws layout (halves): enc16 | encT16 | W16   (dec16 gone — fused kernel casts)
static constexpr size_t WS_ENC = 0;
static constexpr size_t WS_ENCT = WS_ENC + CTX_ELEMS;
static constexpr size_t WS_W = WS_ENCT + CTX_ELEMS;
static constexpr size_t WS_NEEDED_BYTES = (WS_W + ATT_ELEMS) * 2;  // 134.2 MB

__device__ __forceinline__ void async16(const void* g, const void* l) {
  __builtin_amdgcn_global_load_lds(
      (const __attribute__((address_space(1))) unsigned int*)g,
      (__attribute__((address_space(3))) unsigned int*)l, 16, 0, 0);
}

__device__ __forceinline__ f16x8 cvt8(float4 a, float4 b) {
  f16x8 h;
  h[0] = (_Float16)a.x; h[1] = (_Float16)a.y; h[2] = (_Float16)a.z; h[3] = (_Float16)a.w;
  h[4] = (_Float16)b.x; h[5] = (_Float16)b.y; h[6] = (_Float16)b.z; h[7] = (_Float16)b.w;
  return h;
}

// ===========================================================================
// FAST PATH (needs 134 MB ws)
// ===========================================================================

// enc fp32 [b][k][d] -> enc16 fp16 [b][k][d] AND encT16 fp16 [b][d][k].
__global__ __launch_bounds__(256) void convert_enc_kernel(
    const float* __restrict__ enc, _Float16* __restrict__ enc16,
    _Float16* __restrict__ encT) {
  __shared__ _Float16 sT[64 * 72];
  const int k0 = blockIdx.x * 64, d0 = blockIdx.y * 64, b = blockIdx.z;
  const int t = threadIdx.x;
  const int krow = t >> 2;           // 0..63
  const int dcol = (t & 3) * 16;     // 0,16,32,48

  const float* src = enc + ((size_t)b * TK + k0 + krow) * DIM + d0 + dcol;
  float4 f0 = *(const float4*)(src);
  float4 f1 = *(const float4*)(src + 4);
  float4 f2 = *(const float4*)(src + 8);
  float4 f3 = *(const float4*)(src + 12);
  _Float16 h[16];
#pragma unroll
  for (int i = 0; i < 4; i++) {
    h[i]      = (_Float16)((&f0.x)[i]);
    h[i + 4]  = (_Float16)((&f1.x)[i]);
    h[i + 8]  = (_Float16)((&f2.x)[i]);
    h[i + 12] = (_Float16)((&f3.x)[i]);
  }
  _Float16* dsts = enc16 + ((size_t)b * TK + k0 + krow) * DIM + d0 + dcol;
  *(f16x8*)dsts = *(const f16x8*)&h[0];
  *(f16x8*)(dsts + 8) = *(const f16x8*)&h[8];
#pragma unroll
  for (int i = 0; i < 16; i++)
    sT[(dcol + i) * 72 + krow] = h[i];
  __syncthreads();

  const int drow = t >> 2;
  const int kg = (t & 3) * 16;
  f16x8 v0 = *(const f16x8*)&sT[drow * 72 + kg];
  f16x8 v1 = *(const f16x8*)&sT[drow * 72 + kg + 8];
  _Float16* dst = encT + ((size_t)b * DIM + d0 + drow) * TK + k0 + kg;
  *(f16x8*)dst = v0;
  *(f16x8*)(dst + 8) = v1;
}

// ---------------------------------------------------------------------------
// Fused score+mask+softmax: each block owns 32 Q-rows x FULL TK=2048.
// 8 waves; wave w owns cols [w*256, w*256+256). A (dec fp32, 32x1024) is
// cast+staged once into swizzled LDS; B (enc16) streamed register-direct
// from L2. Grid remapped so batch = flat_id & 7 -> all blocks of a batch
// share one XCD's L2 (4 MB = exactly one batch's enc16).
// Epilogue: in-register row softmax (shfl within 16-lane groups + 2 KB LDS
// cross-wave), writes attn fp32 + W16 fp16 directly. No S round-trip.
// ---------------------------------------------------------------------------
__global__ __launch_bounds__(512, 2) void score_softmax_kernel(
    const float* __restrict__ dec, const _Float16* __restrict__ enc16,
    const int* __restrict__ mask, float* __restrict__ attn,
    _Float16* __restrict__ W16) {
  __shared__ _Float16 sA[32 * 1024];   // [row][chunk] with chunk ^= (row&7)
  __shared__ float red[2][32][8];

  const int fid = blockIdx.y * 64 + blockIdx.x;  // grid (64, 8)
  const int b = fid & 7;                         // XCD-pinned batch
  const int mt = fid >> 3;                       // 0..63 row-tile
  const int tid = threadIdx.x;
  const int lane = tid & 63, w = tid >> 6;
  const int tm = lane & 15, quad = lane >> 4;

  const float* Ab = dec + ((size_t)b * TQ + mt * 32) * DIM;
  const _Float16* Bb = enc16 + (size_t)b * TK * DIM;
  const int n0 = w * 256;

  // ---- stage A once: global fp32 (coalesced) -> cvt -> swizzled ds_write
  // thread t handles out-chunks c = t + 512k (chunk = 8 halves = 32B fp32)
#pragma unroll
  for (int k = 0; k < 8; ++k) {
    const int c = tid + 512 * k;
    const int row = c >> 7, cc = c & 127;
    const float* g = Ab + (size_t)row * DIM + cc * 8;
    float4 f0 = *(const float4*)g;
    float4 f1 = *(const float4*)(g + 4);
    *(f16x8*)&sA[(size_t)(row * 128 + (cc ^ (row & 7))) * 8] = cvt8(f0, f1);
  }
  __syncthreads();

  // ---- K loop: barrier-free; B from global (L2-resident), A from LDS
  f32x4 acc[2][16] = {};
  for (int ks = 0; ks < 32; ++ks) {
    f16x8 bF[16];
    const _Float16* bp = Bb + (size_t)(n0 + tm) * DIM + ks * 32 + quad * 8;
#pragma unroll
    for (int j = 0; j < 16; ++j)
      bF[j] = *(const f16x8*)(bp + (size_t)(j * 16) * DIM);
    f16x8 aF[2];
#pragma unroll
    for (int Mt = 0; Mt < 2; ++Mt) {
      const int r = Mt * 16 + tm;
      const int cc = (ks * 4 + quad) ^ (r & 7);
      aF[Mt] = *(const f16x8*)&sA[(size_t)(r * 128 + cc) * 8];
    }
    __builtin_amdgcn_s_setprio(1);
#pragma unroll
    for (int Mt = 0; Mt < 2; ++Mt)
#pragma unroll
      for (int j = 0; j < 16; ++j)
        acc[Mt][j] = __builtin_amdgcn_mfma_f32_16x16x32_f16(
            aF[Mt], bF[j], acc[Mt][j], 0, 0, 0);
    __builtin_amdgcn_s_setprio(0);
  }

  // ---- mask (additive -1e9, matches reference)
  float mk[16];
  const int* mrow = mask + (size_t)b * TK + n0 + tm;
#pragma unroll
  for (int j = 0; j < 16; ++j) mk[j] = mrow[j * 16] ? 0.f : -1e9f;
#pragma unroll
  for (int Mt = 0; Mt < 2; ++Mt)
#pragma unroll
    for (int j = 0; j < 16; ++j)
#pragma unroll
      for (int rr = 0; rr < 4; ++rr)
        acc[Mt][j][rr] += mk[j];

  // ---- row max: lane-local over 16 j, shfl over 16 tm lanes, LDS over waves
  // lane's rows: Mt*16 + quad*4 + rr
  float rmax[2][4];
#pragma unroll
  for (int Mt = 0; Mt < 2; ++Mt)
#pragma unroll
    for (int rr = 0; rr < 4; ++rr) {
      float m = acc[Mt][0][rr];
#pragma unroll
      for (int j = 1; j < 16; ++j) m = fmaxf(m, acc[Mt][j][rr]);
#pragma unroll
      for (int off = 1; off < 16; off <<= 1) m = fmaxf(m, __shfl_xor(m, off));
      rmax[Mt][rr] = m;
    }
  if (tm == 0) {
#pragma unroll
    for (int Mt = 0; Mt < 2; ++Mt)
#pragma unroll
      for (int rr = 0; rr < 4; ++rr)
        red[0][Mt * 16 + quad * 4 + rr][w] = rmax[Mt][rr];
  }
  __syncthreads();
#pragma unroll
  for (int Mt = 0; Mt < 2; ++Mt)
#pragma unroll
    for (int rr = 0; rr < 4; ++rr) {
      const float* rp = red[0][Mt * 16 + quad * 4 + rr];
      float m = rp[0];
#pragma unroll
      for (int i = 1; i < 8; ++i) m = fmaxf(m, rp[i]);
      rmax[Mt][rr] = m;
    }

  // ---- exp + row sum (same reduction tree)
  float rsum[2][4];
#pragma unroll
  for (int Mt = 0; Mt < 2; ++Mt)
#pragma unroll
    for (int rr = 0; rr < 4; ++rr) {
      float s = 0.f;
#pragma unroll
      for (int j = 0; j < 16; ++j) {
        float e = __expf(acc[Mt][j][rr] - rmax[Mt][rr]);
        acc[Mt][j][rr] = e;
        s += e;
      }
#pragma unroll
      for (int off = 1; off < 16; off <<= 1) s += __shfl_xor(s, off);
      rsum[Mt][rr] = s;
    }
  if (tm == 0) {
#pragma unroll
    for (int Mt = 0; Mt < 2; ++Mt)
#pragma unroll
      for (int rr = 0; rr < 4; ++rr)
        red[1][Mt * 16 + quad * 4 + rr][w] = rsum[Mt][rr];
  }
  __syncthreads();
#pragma unroll
  for (int Mt = 0; Mt < 2; ++Mt)
#pragma unroll
    for (int rr = 0; rr < 4; ++rr) {
      const float* rp = red[1][Mt * 16 + quad * 4 + rr];
      float s = rp[0];
#pragma unroll
      for (int i = 1; i < 8; ++i) s += rp[i];
      rsum[Mt][rr] = s;
    }

  // ---- write attn fp32 + W16 fp16
#pragma unroll
  for (int Mt = 0; Mt < 2; ++Mt)
#pragma unroll
    for (int rr = 0; rr < 4; ++rr) {
      const float inv = 1.0f / rsum[Mt][rr];
      const size_t grow = (size_t)b * TQ + mt * 32 + Mt * 16 + quad * 4 + rr;
      float* ap = attn + grow * (size_t)TK + n0 + tm;
      _Float16* wp = W16 + grow * (size_t)TK + n0 + tm;
#pragma unroll
      for (int j = 0; j < 16; ++j) {
        float o = acc[Mt][j][rr] * inv;
        ap[j * 16] = o;
        wp[j * 16] = (_Float16)o;
      }
    }
}

// ---------------------------------------------------------------------------
// 8-phase 256x256 NT GEMM, BK=64, 512 threads (8 waves, 2x4), 128 KB LDS.
// Round-3 verified core (coalesced DMA + chunk-XOR swizzle + counted vmcnt).
// Used for the context GEMM: ctx = W16 @ encT.
// ---------------------------------------------------------------------------
template <int KD>
__device__ __forceinline__ void stage_sub(const _Float16* __restrict__ Xb,
                                          _Float16* slot, int khalf,
                                          int w, int srow, int schunk) {
#pragma unroll
  for (int j = 0; j < 2; ++j) {
    const int row0 = 16 * (j * 8 + w);
    async16(Xb + (size_t)(row0 + srow) * KD + khalf + schunk * 8,
            slot + row0 * 32);
  }
}

__device__ __forceinline__ void load4s(f16x8 (&dst)[4], const _Float16* base) {
#pragma unroll
  for (int i = 0; i < 4; ++i) dst[i] = *(const f16x8*)(base + i * 512);
}

__device__ __forceinline__ void mfma16(f32x4 (&acc)[8][4], const f16x8 (&aF)[4],
                                       const f16x8 (&bF)[4], int mh) {
  __builtin_amdgcn_s_setprio(1);
#pragma unroll
  for (int i = 0; i < 4; ++i)
#pragma unroll
    for (int j = 0; j < 4; ++j)
      acc[mh * 4 + i][j] = __builtin_amdgcn_mfma_f32_16x16x32_f16(
          aF[i], bF[j], acc[mh * 4 + i][j], 0, 0, 0);
  __builtin_amdgcn_s_setprio(0);
}

template <int M, int N, int K>
__global__ __launch_bounds__(512, 2) void gemm8p(
    const _Float16* __restrict__ A, const _Float16* __restrict__ B,
    float* __restrict__ C) {
  __shared__ _Float16 lds[65536];  // 128 KB: A_lo[2]|A_hi[2]|B_lo[2]|B_hi[2]
  constexpr int T = K / 64;

  const int b = blockIdx.x, nt = blockIdx.y, mt = blockIdx.z;
  const int tid = threadIdx.x;
  const int lane = tid & 63, w = tid >> 6;
  const int tm = lane & 15, quad = lane >> 4;
  const int wr = w >> 2, wc = w & 3;   // 2x4 wave grid; wave tile 128x64

  const _Float16* Ab = A + ((size_t)b * M + mt * 256) * K;
  const _Float16* Bb = B + ((size_t)b * N + nt * 256) * K;

  const int srow = lane >> 2;                    // 0..15
  const int schunk = (lane & 3) ^ (srow & 3);    // XOR swizzle

  const int xorc = (quad ^ (tm & 3)) * 8;
  const int aBase = (wr * 128 + tm) * 32 + xorc;
  const int bBase = (wc * 64 + tm) * 32 + xorc;

  f32x4 acc[8][4] = {};

  stage_sub<K>(Ab, lds, 0, w, srow, schunk);                    // A_lo(0)
  stage_sub<K>(Bb, lds + 32768, 0, w, srow, schunk);            // B_lo(0)
  stage_sub<K>(Ab, lds + 16384, 32, w, srow, schunk);           // A_hi(0)
  stage_sub<K>(Bb, lds + 49152, 32, w, srow, schunk);           // B_hi(0)
  stage_sub<K>(Ab, lds + 8192, 64, w, srow, schunk);            // A_lo(1)
  stage_sub<K>(Bb, lds + 32768 + 8192, 64, w, srow, schunk);    // B_lo(1)
  asm volatile("s_waitcnt vmcnt(8)" ::: "memory");
  __builtin_amdgcn_s_barrier();

  for (int t = 0; t < T; ++t) {
    const int p = t & 1, np = p ^ 1;
    _Float16* const aLo = lds + p * 8192;
    _Float16* const aHi = lds + 16384 + p * 8192;
    _Float16* const bLo = lds + 32768 + p * 8192;
    _Float16* const bHi = lds + 49152 + p * 8192;
    const bool s1 = (t + 1 < T), s2 = (t + 2 < T);
    f16x8 aF[4], bF[4];

    load4s(aF, aLo + aBase);
    load4s(bF, bLo + bBase);
    if (s1) stage_sub<K>(Ab, lds + 16384 + np * 8192, (t + 1) * 64 + 32, w, srow, schunk);
    __builtin_amdgcn_s_barrier();
    mfma16(acc, aF, bF, 0);
    __builtin_amdgcn_s_barrier();

    load4s(aF, aLo + aBase + 2048);
    if (s1) {
      stage_sub<K>(Bb, lds + 49152 + np * 8192, (t + 1) * 64 + 32, w, srow, schunk);
      asm volatile("s_waitcnt vmcnt(8)" ::: "memory");
    } else {
      asm volatile("s_waitcnt vmcnt(0)" ::: "memory");
    }
    __builtin_amdgcn_s_barrier();
    mfma16(acc, aF, bF, 1);
    __builtin_amdgcn_s_barrier();

    load4s(aF, aHi + aBase);
    load4s(bF, bHi + bBase);
    if (s2) stage_sub<K>(Ab, lds + p * 8192, (t + 2) * 64, w, srow, schunk);
    __builtin_amdgcn_s_barrier();
    mfma16(acc, aF, bF, 0);
    __builtin_amdgcn_s_barrier();

    load4s(aF, aHi + aBase + 2048);
    if (s2) {
      stage_sub<K>(Bb, lds + 32768 + p * 8192, (t + 2) * 64, w, srow, schunk);
      asm volatile("s_waitcnt vmcnt(8)" ::: "memory");
    } else if (t + 2 == T) {
      asm volatile("s_waitcnt vmcnt(4)" ::: "memory");
    }
    __builtin_amdgcn_s_barrier();
    mfma16(acc, aF, bF, 1);
    __builtin_amdgcn_s_barrier();
  }

#pragma unroll
  for (int i = 0; i < 8; ++i) {
#pragma unroll
    for (int rr = 0; rr < 4; ++rr) {
      size_t row = (size_t)b * M + mt * 256 + wr * 128 + i * 16 + quad * 4 + rr;
      float* Crow = C + row * (size_t)N + nt * 256 + wc * 64 + tm;
#pragma unroll
      for (int j = 0; j < 4; ++j) Crow[j * 16] = acc[i][j][rr];
    }
  }
}

// masked softmax in-place over S rows (fallback path only).
__global__ __launch_bounds__(256) void softmax_kernel(
    float* __restrict__ S, const int* __restrict__ mask, _Float16* __restrict__ W16) {
  const int row = blockIdx.x;
  const int b = row >> 11;
  float* srow = S + (size_t)row * TK;
  const int* mrow = mask + (size_t)b * TK;
  const int t = threadIdx.x;

  float4 s0 = *(const float4*)(srow + t * 8);
  float4 s1 = *(const float4*)(srow + t * 8 + 4);
  int4 m0 = *(const int4*)(mrow + t * 8);
  int4 m1 = *(const int4*)(mrow + t * 8 + 4);

  float v[8] = {s0.x, s0.y, s0.z, s0.w, s1.x, s1.y, s1.z, s1.w};
  const int mm[8] = {m0.x, m0.y, m0.z, m0.w, m1.x, m1.y, m1.z, m1.w};
#pragma unroll
  for (int i = 0; i < 8; i++)
    if (!mm[i]) v[i] += -1e9f;

  float mx = v[0];
#pragma unroll
  for (int i = 1; i < 8; i++) mx = fmaxf(mx, v[i]);
#pragma unroll
  for (int off = 32; off > 0; off >>= 1) mx = fmaxf(mx, __shfl_down(mx, off));

  __shared__ float redm[4];
  __shared__ float reds[4];
  if ((t & 63) == 0) redm[t >> 6] = mx;
  __syncthreads();
  mx = fmaxf(fmaxf(redm[0], redm[1]), fmaxf(redm[2], redm[3]));

  float e[8];
  float lsum = 0.f;
#pragma unroll
  for (int i = 0; i < 8; i++) {
    e[i] = __expf(v[i] - mx);
    lsum += e[i];
  }
#pragma unroll
  for (int off = 32; off > 0; off >>= 1) lsum += __shfl_down(lsum, off);
  if ((t & 63) == 0) reds[t >> 6] = lsum;
  __syncthreads();
  const float inv = 1.0f / (reds[0] + reds[1] + reds[2] + reds[3]);

  float4 o0 = {e[0] * inv, e[1] * inv, e[2] * inv, e[3] * inv};
  float4 o1 = {e[4] * inv, e[5] * inv, e[6] * inv, e[7] * inv};
  *(float4*)(srow + t * 8) = o0;
  *(float4*)(srow + t * 8 + 4) = o1;
  if (W16) {
    f16x8 h;
    h[0] = (_Float16)o0.x; h[1] = (_Float16)o0.y; h[2] = (_Float16)o0.z; h[3] = (_Float16)o0.w;
    h[4] = (_Float16)o1.x; h[5] = (_Float16)o1.y; h[6] = (_Float16)o1.z; h[7] = (_Float16)o1.w;
    *(f16x8*)(W16 + (size_t)row * TK + t * 8) = h;
  }
}

// ===========================================================================
// FALLBACK PATH (used only if ws too small)
// ===========================================================================
static constexpr int BM = 128, BN = 128, BK = 32;
static constexpr int LDSS = 40;

__global__ __launch_bounds__(256) void score_kernel_fb(
    const float* __restrict__ dec, const float* __restrict__ enc,
    float* __restrict__ S) {
  __shared__ _Float16 sA[BM * LDSS];
  __shared__ _Float16 sB[BN * LDSS];
  const int nt = blockIdx.x, mt = blockIdx.y, b = blockIdx.z;
  const int t = threadIdx.x;
  const int lane = t & 63, wave = t >> 6;
  const int wm = wave >> 1, wn = wave & 1;
  const int tm = lane & 15, quad = lane >> 4;
  const float* Abase = dec + ((size_t)b * TQ + mt * BM) * DIM;
  const float* Bbase = enc + ((size_t)b * TK + nt * BN) * DIM;
  f32x4 acc[4][4] = {};
  const int r = t >> 2;
  const int c8 = (t & 3) * 8;
  for (int k0 = 0; k0 < DIM; k0 += BK) {
    float4 a0 = *(const float4*)(Abase + (size_t)r * DIM + k0 + c8);
    float4 a1 = *(const float4*)(Abase + (size_t)r * DIM + k0 + c8 + 4);
    float4 a2 = *(const float4*)(Abase + (size_t)(r + 64) * DIM + k0 + c8);
    float4 a3 = *(const float4*)(Abase + (size_t)(r + 64) * DIM + k0 + c8 + 4);
    float4 b0 = *(const float4*)(Bbase + (size_t)r * DIM + k0 + c8);
    float4 b1 = *(const float4*)(Bbase + (size_t)r * DIM + k0 + c8 + 4);
    float4 b2 = *(const float4*)(Bbase + (size_t)(r + 64) * DIM + k0 + c8);
    float4 b3 = *(const float4*)(Bbase + (size_t)(r + 64) * DIM + k0 + c8 + 4);
    __syncthreads();
    *(f16x8*)&sA[r * LDSS + c8] = cvt8(a0, a1);
    *(f16x8*)&sA[(r + 64) * LDSS + c8] = cvt8(a2, a3);
    *(f16x8*)&sB[r * LDSS + c8] = cvt8(b0, b1);
    *(f16x8*)&sB[(r + 64) * LDSS + c8] = cvt8(b2, b3);
    __syncthreads();
    f16x8 aF[4], bF[4];
#pragma unroll
    for (int i = 0; i < 4; i++)
      aF[i] = *(const f16x8*)&sA[(wm * 64 + i * 16 + tm) * LDSS + quad * 8];
#pragma unroll
    for (int j = 0; j < 4; j++)
      bF[j] = *(const f16x8*)&sB[(wn * 64 + j * 16 + tm) * LDSS + quad * 8];
#pragma unroll
    for (int i = 0; i < 4; i++)
#pragma unroll
      for (int j = 0; j < 4; j++)
        acc[i][j] = __builtin_amdgcn_mfma_f32_16x16x32_f16(aF[i], bF[j], acc[i][j], 0, 0, 0);
  }
#pragma unroll
  for (int i = 0; i < 4; i++) {
#pragma unroll
    for (int rr = 0; rr < 4; rr++) {
      size_t rowoff = ((size_t)b * TQ + mt * BM + wm * 64 + i * 16 + quad * 4 + rr) * (size_t)TK;
#pragma unroll
      for (int j = 0; j < 4; j++)
        S[rowoff + nt * BN + wn * 64 + j * 16 + tm] = acc[i][j][rr];
    }
  }
}

__global__ __launch_bounds__(256) void ctx_kernel_fb(
    const float* __restrict__ W, const float* __restrict__ enc,
    float* __restrict__ C) {
  __shared__ _Float16 sA[BM * LDSS];
  __shared__ _Float16 sB[BN * LDSS];
  const int nt = blockIdx.x;
  const int mt = blockIdx.y;
  const int b = blockIdx.z;
  const int t = threadIdx.x;
  const int lane = t & 63, wave = t >> 6;
  const int wm = wave >> 1, wn = wave & 1;
  const int tm = lane & 15, quad = lane >> 4;
  const float* Abase = W + ((size_t)b * TQ + mt * BM) * TK;
  const float* Ebase = enc + (size_t)b * TK * DIM + nt * BN;
  f32x4 acc[4][4] = {};
  const int r = t >> 2;
  const int c8 = (t & 3) * 8;
  const int kkB = (t & 7) * 4;
  const int nnB = (t >> 3) * 4;
  for (int k0 = 0; k0 < TK; k0 += BK) {
    float4 a0 = *(const float4*)(Abase + (size_t)r * TK + k0 + c8);
    float4 a1 = *(const float4*)(Abase + (size_t)r * TK + k0 + c8 + 4);
    float4 a2 = *(const float4*)(Abase + (size_t)(r + 64) * TK + k0 + c8);
    float4 a3 = *(const float4*)(Abase + (size_t)(r + 64) * TK + k0 + c8 + 4);
    float4 f[4];
#pragma unroll
    for (int i = 0; i < 4; i++)
      f[i] = *(const float4*)(Ebase + (size_t)(k0 + kkB + i) * DIM + nnB);
    __syncthreads();
    *(f16x8*)&sA[r * LDSS + c8] = cvt8(a0, a1);
    *(f16x8*)&sA[(r + 64) * LDSS + c8] = cvt8(a2, a3);
#pragma unroll
    for (int c = 0; c < 4; c++) {
      f16x4 h;
      h[0] = (_Float16)((&f[0].x)[c]);
      h[1] = (_Float16)((&f[1].x)[c]);
      h[2] = (_Float16)((&f[2].x)[c]);
      h[3] = (_Float16)((&f[3].x)[c]);
      *(f16x4*)&sB[(nnB + c) * LDSS + kkB] = h;
    }
    __syncthreads();
    f16x8 aF[4], bF[4];
#pragma unroll
    for (int i = 0; i < 4; i++)
      aF[i] = *(const f16x8*)&sA[(wm * 64 + i * 16 + tm) * LDSS + quad * 8];
#pragma unroll
    for (int j = 0; j < 4; j++)
      bF[j] = *(const f16x8*)&sB[(wn * 64 + j * 16 + tm) * LDSS + quad * 8];
#pragma unroll
    for (int i = 0; i < 4; i++)
#pragma unroll
      for (int j = 0; j < 4; j++)
        acc[i][j] = __builtin_amdgcn_mfma_f32_16x16x32_f16(aF[i], bF[j], acc[i][j], 0, 0, 0);
  }
#pragma unroll
  for (int i = 0; i < 4; i++) {
#pragma unroll
    for (int rr = 0; rr < 4; rr++) {
      size_t rowoff = ((size_t)b * TQ + mt * BM + wm * 64 + i * 16 + quad * 4 + rr) * (size_t)DIM;
#pragma unroll
      for (int j = 0; j < 4; j++)
        C[rowoff + nt * BN + wn * 64 + j * 16 + tm] = acc[i][j][rr];
    }
  }
}

// ===========================================================================
extern "C" void kernel_launch(void* const* d_in, const int* in_sizes, int n_in,
                              void* d_out, int out_size, void* d_ws, size_t ws_size,
                              hipStream_t stream) {
  const float* dec = (const float*)d_in[0];
  const float* enc = (const float*)d_in[1];
  const int* mask = (const int*)d_in[2];

  float* ctx = (float*)d_out;               // [8, 2048, 1024]
  float* attn = (float*)d_out + CTX_ELEMS;  // [8, 2048, 2048]

  dim3 block(256);

  if (ws_size >= WS_NEEDED_BYTES) {
    _Float16* enc16 = (_Float16*)d_ws + WS_ENC;
    _Float16* encT = (_Float16*)d_ws + WS_ENCT;
    _Float16* W16 = (_Float16*)d_ws + WS_W;

    convert_enc_kernel<<<dim3(TK / 64, DIM / 64, BATCH), block, 0, stream>>>(enc, enc16, encT);
    // fused score+mask+softmax: grid (mt=64, b=8), batch pinned per XCD
    score_softmax_kernel<<<dim3(64, 8), dim3(512), 0, stream>>>(dec, enc16, mask, attn, W16);
    gemm8p<TQ, DIM, TK><<<dim3(BATCH, DIM / 256, TQ / 256), dim3(512), 0, stream>>>(W16, encT, ctx);
  } else {
    score_kernel_fb<<<dim3(TK / BN, TQ / BM, BATCH), block, 0, stream>>>(dec, enc, attn);
    softmax_kernel<<<dim3(BATCH * TQ), block, 0, stream>>>(attn, mask, nullptr);
    ctx_kernel_fb<<<dim3(DIM / BN, TQ / BM, BATCH), block, 0, stream>>>(attn, enc, ctx);
  }
}

// Round 7
// 488.314 us; speedup vs baseline: 1.2379x; 1.2379x over previous
//
#include <hip/hip_runtime.h>
#include <cstddef>
#include <cstdint>

typedef _Float16 f16x8 __attribute__((ext_vector_type(8)));
typedef _Float16 f16x4 __attribute__((ext_vector_type(4)));
typedef float f32x4 __attribute__((ext_vector_type(4)));

static constexpr int BATCH = 8;
static constexpr int TQ = 2048;
static constexpr int TK = 2048;
static constexpr int DIM = 1024;
static constexpr size_t CTX_ELEMS = (size_t)BATCH * TQ * DIM;   // 16,777,216
static constexpr size_t ATT_ELEMS = (size_t)BATCH * TQ * TK;    // 33,554,432

// ws layout (halves): dec16 | enc16 | encT16 | W16
static constexpr size_t WS_DEC = 0;
static constexpr size_t WS_ENC = WS_DEC + CTX_ELEMS;
static constexpr size_t WS_ENCT = WS_ENC + CTX_ELEMS;
static constexpr size_t WS_W = WS_ENCT + CTX_ELEMS;
static constexpr size_t WS_NEEDED_BYTES = (WS_W + ATT_ELEMS) * 2;  // 167.8 MB

__device__ __forceinline__ void async16(const void* g, const void* l) {
  __builtin_amdgcn_global_load_lds(
      (const __attribute__((address_space(1))) unsigned int*)g,
      (__attribute__((address_space(3))) unsigned int*)l, 16, 0, 0);
}

__device__ __forceinline__ f16x8 cvt8(float4 a, float4 b) {
  f16x8 h;
  h[0] = (_Float16)a.x; h[1] = (_Float16)a.y; h[2] = (_Float16)a.z; h[3] = (_Float16)a.w;
  h[4] = (_Float16)b.x; h[5] = (_Float16)b.y; h[6] = (_Float16)b.z; h[7] = (_Float16)b.w;
  return h;
}

// ===========================================================================
// FAST PATH (needs 168 MB ws)
// ===========================================================================

// enc fp32 [b][k][d] -> enc16 [b][k][d] AND encT16 [b][d][k];
// PLUS (merged) dec fp32 -> dec16 elementwise (each block converts one
// 4096-float chunk; 4096 blocks x 4096 = CTX_ELEMS exactly).
__global__ __launch_bounds__(256) void convert_kernel(
    const float* __restrict__ enc, const float* __restrict__ dec,
    _Float16* __restrict__ enc16, _Float16* __restrict__ encT,
    _Float16* __restrict__ dec16) {
  __shared__ _Float16 sT[64 * 72];
  const int k0 = blockIdx.x * 64, d0 = blockIdx.y * 64, b = blockIdx.z;
  const int t = threadIdx.x;
  const int krow = t >> 2;           // 0..63
  const int dcol = (t & 3) * 16;     // 0,16,32,48

  const float* src = enc + ((size_t)b * TK + k0 + krow) * DIM + d0 + dcol;
  float4 f0 = *(const float4*)(src);
  float4 f1 = *(const float4*)(src + 4);
  float4 f2 = *(const float4*)(src + 8);
  float4 f3 = *(const float4*)(src + 12);
  _Float16 h[16];
#pragma unroll
  for (int i = 0; i < 4; i++) {
    h[i]      = (_Float16)((&f0.x)[i]);
    h[i + 4]  = (_Float16)((&f1.x)[i]);
    h[i + 8]  = (_Float16)((&f2.x)[i]);
    h[i + 12] = (_Float16)((&f3.x)[i]);
  }
  _Float16* dsts = enc16 + ((size_t)b * TK + k0 + krow) * DIM + d0 + dcol;
  *(f16x8*)dsts = *(const f16x8*)&h[0];
  *(f16x8*)(dsts + 8) = *(const f16x8*)&h[8];
#pragma unroll
  for (int i = 0; i < 16; i++)
    sT[(dcol + i) * 72 + krow] = h[i];

  // merged dec conversion (independent of the enc/LDS dataflow)
  {
    const int bid = ((blockIdx.z * gridDim.y) + blockIdx.y) * gridDim.x + blockIdx.x;
    size_t base = (size_t)bid * 4096 + (size_t)t * 16;
    float4 a0 = *(const float4*)(dec + base);
    float4 a1 = *(const float4*)(dec + base + 4);
    float4 a2 = *(const float4*)(dec + base + 8);
    float4 a3 = *(const float4*)(dec + base + 12);
    *(f16x8*)(dec16 + base) = cvt8(a0, a1);
    *(f16x8*)(dec16 + base + 8) = cvt8(a2, a3);
  }

  __syncthreads();

  const int drow = t >> 2;
  const int kg = (t & 3) * 16;
  f16x8 v0 = *(const f16x8*)&sT[drow * 72 + kg];
  f16x8 v1 = *(const f16x8*)&sT[drow * 72 + kg + 8];
  _Float16* dst = encT + ((size_t)b * DIM + d0 + drow) * TK + k0 + kg;
  *(f16x8*)dst = v0;
  *(f16x8*)(dst + 8) = v1;
}

// ---------------------------------------------------------------------------
// 256x256 NT GEMM, BK=64, 512 threads (8 waves, 2x4), 128 KB LDS.
// Round-3 verified core (coalesced DMA + chunk-XOR swizzle + counted vmcnt)
// with MERGED PHASES: one phase computes the full 128-row wave tile per
// k-sub (12 ds_reads + 32 MFMAs per barrier region instead of 2x(6+16)).
// Halves barrier count per K-tile (8 -> 4); same staging/vmcnt retirement
// points as the verified schedule (invariant: 8 loads outstanding at loop
// top; vmcnt(8) after each 4-load stage pair; tail vmcnt(4)/vmcnt(0)).
// ---------------------------------------------------------------------------
template <int KD>
__device__ __forceinline__ void stage_sub(const _Float16* __restrict__ Xb,
                                          _Float16* slot, int khalf,
                                          int w, int srow, int schunk) {
#pragma unroll
  for (int j = 0; j < 2; ++j) {
    const int row0 = 16 * (j * 8 + w);
    async16(Xb + (size_t)(row0 + srow) * KD + khalf + schunk * 8,
            slot + row0 * 32);
  }
}

__device__ __forceinline__ void load4s(f16x8* dst, const _Float16* base) {
#pragma unroll
  for (int i = 0; i < 4; ++i) dst[i] = *(const f16x8*)(base + i * 512);
}

__device__ __forceinline__ void mfma32(f32x4 (&acc)[8][4], const f16x8 (&aF)[8],
                                       const f16x8 (&bF)[4]) {
  __builtin_amdgcn_s_setprio(1);
#pragma unroll
  for (int i = 0; i < 8; ++i)
#pragma unroll
    for (int j = 0; j < 4; ++j)
      acc[i][j] = __builtin_amdgcn_mfma_f32_16x16x32_f16(
          aF[i], bF[j], acc[i][j], 0, 0, 0);
  __builtin_amdgcn_s_setprio(0);
}

template <int M, int N, int K>
__global__ __launch_bounds__(512, 2) void gemm8p(
    const _Float16* __restrict__ A, const _Float16* __restrict__ B,
    float* __restrict__ C) {
  __shared__ _Float16 lds[65536];  // 128 KB: A_lo[2]|A_hi[2]|B_lo[2]|B_hi[2]
  constexpr int T = K / 64;

  const int b = blockIdx.x, nt = blockIdx.y, mt = blockIdx.z;
  const int tid = threadIdx.x;
  const int lane = tid & 63, w = tid >> 6;
  const int tm = lane & 15, quad = lane >> 4;
  const int wr = w >> 2, wc = w & 3;   // 2x4 wave grid; wave tile 128x64

  const _Float16* Ab = A + ((size_t)b * M + mt * 256) * K;
  const _Float16* Bb = B + ((size_t)b * N + nt * 256) * K;

  // staging lane geometry (swizzled source chunk, within same 64B row window)
  const int srow = lane >> 2;                    // 0..15
  const int schunk = (lane & 3) ^ (srow & 3);    // XOR swizzle

  // fragment read bases (halves within an 8192-half slot); row ≡ tm (mod 4)
  const int xorc = (quad ^ (tm & 3)) * 8;
  const int aBase = (wr * 128 + tm) * 32 + xorc;
  const int bBase = (wc * 64 + tm) * 32 + xorc;

  f32x4 acc[8][4] = {};

  // prologue: lo(0), hi(0), lo(1) staged (12 loads); wait for lo(0)
  stage_sub<K>(Ab, lds, 0, w, srow, schunk);                    // A_lo(0)
  stage_sub<K>(Bb, lds + 32768, 0, w, srow, schunk);            // B_lo(0)
  stage_sub<K>(Ab, lds + 16384, 32, w, srow, schunk);           // A_hi(0)
  stage_sub<K>(Bb, lds + 49152, 32, w, srow, schunk);           // B_hi(0)
  stage_sub<K>(Ab, lds + 8192, 64, w, srow, schunk);            // A_lo(1)
  stage_sub<K>(Bb, lds + 32768 + 8192, 64, w, srow, schunk);    // B_lo(1)
  asm volatile("s_waitcnt vmcnt(8)" ::: "memory");
  __builtin_amdgcn_s_barrier();

  for (int t = 0; t < T; ++t) {
    const int p = t & 1, np = p ^ 1;
    _Float16* const aLo = lds + p * 8192;
    _Float16* const aHi = lds + 16384 + p * 8192;
    _Float16* const bLo = lds + 32768 + p * 8192;
    _Float16* const bHi = lds + 49152 + p * 8192;
    const bool s1 = (t + 1 < T), s2 = (t + 2 < T);
    f16x8 aF[8], bF[4];

    // ---- phase A: rows 0-127 of wave tile, k-sub lo
    load4s(&aF[0], aLo + aBase);
    load4s(&aF[4], aLo + aBase + 2048);
    load4s(&bF[0], bLo + bBase);
    if (s1) {
      stage_sub<K>(Ab, lds + 16384 + np * 8192, (t + 1) * 64 + 32, w, srow, schunk);
      stage_sub<K>(Bb, lds + 49152 + np * 8192, (t + 1) * 64 + 32, w, srow, schunk);
      asm volatile("s_waitcnt vmcnt(8)" ::: "memory");   // hi(t) landed
    } else {
      asm volatile("s_waitcnt vmcnt(0)" ::: "memory");
    }
    __builtin_amdgcn_s_barrier();
    mfma32(acc, aF, bF);
    __builtin_amdgcn_s_barrier();

    // ---- phase B: rows 0-127, k-sub hi
    load4s(&aF[0], aHi + aBase);
    load4s(&aF[4], aHi + aBase + 2048);
    load4s(&bF[0], bHi + bBase);
    if (s2) {
      stage_sub<K>(Ab, lds + p * 8192, (t + 2) * 64, w, srow, schunk);
      stage_sub<K>(Bb, lds + 32768 + p * 8192, (t + 2) * 64, w, srow, schunk);
      asm volatile("s_waitcnt vmcnt(8)" ::: "memory");   // lo(t+1) landed
    } else if (t + 2 == T) {
      asm volatile("s_waitcnt vmcnt(4)" ::: "memory");   // lo(T-1) landed
    }
    __builtin_amdgcn_s_barrier();
    mfma32(acc, aF, bF);
    __builtin_amdgcn_s_barrier();
  }

  // C/D layout: col = tm, row = quad*4 + rr; acc[i] covers rows i*16
#pragma unroll
  for (int i = 0; i < 8; ++i) {
#pragma unroll
    for (int rr = 0; rr < 4; ++rr) {
      size_t row = (size_t)b * M + mt * 256 + wr * 128 + i * 16 + quad * 4 + rr;
      float* Crow = C + row * (size_t)N + nt * 256 + wc * 64 + tm;
#pragma unroll
      for (int j = 0; j < 4; ++j) Crow[j * 16] = acc[i][j][rr];
    }
  }
}

// masked softmax in-place over S rows; optionally also emits fp16 copy.
__global__ __launch_bounds__(256) void softmax_kernel(
    float* __restrict__ S, const int* __restrict__ mask, _Float16* __restrict__ W16) {
  const int row = blockIdx.x;
  const int b = row >> 11;
  float* srow = S + (size_t)row * TK;
  const int* mrow = mask + (size_t)b * TK;
  const int t = threadIdx.x;

  float4 s0 = *(const float4*)(srow + t * 8);
  float4 s1 = *(const float4*)(srow + t * 8 + 4);
  int4 m0 = *(const int4*)(mrow + t * 8);
  int4 m1 = *(const int4*)(mrow + t * 8 + 4);

  float v[8] = {s0.x, s0.y, s0.z, s0.w, s1.x, s1.y, s1.z, s1.w};
  const int mm[8] = {m0.x, m0.y, m0.z, m0.w, m1.x, m1.y, m1.z, m1.w};
#pragma unroll
  for (int i = 0; i < 8; i++)
    if (!mm[i]) v[i] += -1e9f;

  float mx = v[0];
#pragma unroll
  for (int i = 1; i < 8; i++) mx = fmaxf(mx, v[i]);
#pragma unroll
  for (int off = 32; off > 0; off >>= 1) mx = fmaxf(mx, __shfl_down(mx, off));

  __shared__ float redm[4];
  __shared__ float reds[4];
  if ((t & 63) == 0) redm[t >> 6] = mx;
  __syncthreads();
  mx = fmaxf(fmaxf(redm[0], redm[1]), fmaxf(redm[2], redm[3]));

  float e[8];
  float lsum = 0.f;
#pragma unroll
  for (int i = 0; i < 8; i++) {
    e[i] = __expf(v[i] - mx);
    lsum += e[i];
  }
#pragma unroll
  for (int off = 32; off > 0; off >>= 1) lsum += __shfl_down(lsum, off);
  if ((t & 63) == 0) reds[t >> 6] = lsum;
  __syncthreads();
  const float inv = 1.0f / (reds[0] + reds[1] + reds[2] + reds[3]);

  float4 o0 = {e[0] * inv, e[1] * inv, e[2] * inv, e[3] * inv};
  float4 o1 = {e[4] * inv, e[5] * inv, e[6] * inv, e[7] * inv};
  *(float4*)(srow + t * 8) = o0;
  *(float4*)(srow + t * 8 + 4) = o1;
  if (W16) {
    f16x8 h;
    h[0] = (_Float16)o0.x; h[1] = (_Float16)o0.y; h[2] = (_Float16)o0.z; h[3] = (_Float16)o0.w;
    h[4] = (_Float16)o1.x; h[5] = (_Float16)o1.y; h[6] = (_Float16)o1.z; h[7] = (_Float16)o1.w;
    *(f16x8*)(W16 + (size_t)row * TK + t * 8) = h;
  }
}

// ===========================================================================
// FALLBACK PATH (used only if ws too small)
// ===========================================================================
static constexpr int BM = 128, BN = 128, BK = 32;
static constexpr int LDSS = 40;

__global__ __launch_bounds__(256) void score_kernel_fb(
    const float* __restrict__ dec, const float* __restrict__ enc,
    float* __restrict__ S) {
  __shared__ _Float16 sA[BM * LDSS];
  __shared__ _Float16 sB[BN * LDSS];
  const int nt = blockIdx.x, mt = blockIdx.y, b = blockIdx.z;
  const int t = threadIdx.x;
  const int lane = t & 63, wave = t >> 6;
  const int wm = wave >> 1, wn = wave & 1;
  const int tm = lane & 15, quad = lane >> 4;
  const float* Abase = dec + ((size_t)b * TQ + mt * BM) * DIM;
  const float* Bbase = enc + ((size_t)b * TK + nt * BN) * DIM;
  f32x4 acc[4][4] = {};
  const int r = t >> 2;
  const int c8 = (t & 3) * 8;
  for (int k0 = 0; k0 < DIM; k0 += BK) {
    float4 a0 = *(const float4*)(Abase + (size_t)r * DIM + k0 + c8);
    float4 a1 = *(const float4*)(Abase + (size_t)r * DIM + k0 + c8 + 4);
    float4 a2 = *(const float4*)(Abase + (size_t)(r + 64) * DIM + k0 + c8);
    float4 a3 = *(const float4*)(Abase + (size_t)(r + 64) * DIM + k0 + c8 + 4);
    float4 b0 = *(const float4*)(Bbase + (size_t)r * DIM + k0 + c8);
    float4 b1 = *(const float4*)(Bbase + (size_t)r * DIM + k0 + c8 + 4);
    float4 b2 = *(const float4*)(Bbase + (size_t)(r + 64) * DIM + k0 + c8);
    float4 b3 = *(const float4*)(Bbase + (size_t)(r + 64) * DIM + k0 + c8 + 4);
    __syncthreads();
    *(f16x8*)&sA[r * LDSS + c8] = cvt8(a0, a1);
    *(f16x8*)&sA[(r + 64) * LDSS + c8] = cvt8(a2, a3);
    *(f16x8*)&sB[r * LDSS + c8] = cvt8(b0, b1);
    *(f16x8*)&sB[(r + 64) * LDSS + c8] = cvt8(b2, b3);
    __syncthreads();
    f16x8 aF[4], bF[4];
#pragma unroll
    for (int i = 0; i < 4; i++)
      aF[i] = *(const f16x8*)&sA[(wm * 64 + i * 16 + tm) * LDSS + quad * 8];
#pragma unroll
    for (int j = 0; j < 4; j++)
      bF[j] = *(const f16x8*)&sB[(wn * 64 + j * 16 + tm) * LDSS + quad * 8];
#pragma unroll
    for (int i = 0; i < 4; i++)
#pragma unroll
      for (int j = 0; j < 4; j++)
        acc[i][j] = __builtin_amdgcn_mfma_f32_16x16x32_f16(aF[i], bF[j], acc[i][j], 0, 0, 0);
  }
#pragma unroll
  for (int i = 0; i < 4; i++) {
#pragma unroll
    for (int rr = 0; rr < 4; rr++) {
      size_t rowoff = ((size_t)b * TQ + mt * BM + wm * 64 + i * 16 + quad * 4 + rr) * (size_t)TK;
#pragma unroll
      for (int j = 0; j < 4; j++)
        S[rowoff + nt * BN + wn * 64 + j * 16 + tm] = acc[i][j][rr];
    }
  }
}

__global__ __launch_bounds__(256) void ctx_kernel_fb(
    const float* __restrict__ W, const float* __restrict__ enc,
    float* __restrict__ C) {
  __shared__ _Float16 sA[BM * LDSS];
  __shared__ _Float16 sB[BN * LDSS];
  const int nt = blockIdx.x;
  const int mt = blockIdx.y;
  const int b = blockIdx.z;
  const int t = threadIdx.x;
  const int lane = t & 63, wave = t >> 6;
  const int wm = wave >> 1, wn = wave & 1;
  const int tm = lane & 15, quad = lane >> 4;
  const float* Abase = W + ((size_t)b * TQ + mt * BM) * TK;
  const float* Ebase = enc + (size_t)b * TK * DIM + nt * BN;
  f32x4 acc[4][4] = {};
  const int r = t >> 2;
  const int c8 = (t & 3) * 8;
  const int kkB = (t & 7) * 4;
  const int nnB = (t >> 3) * 4;
  for (int k0 = 0; k0 < TK; k0 += BK) {
    float4 a0 = *(const float4*)(Abase + (size_t)r * TK + k0 + c8);
    float4 a1 = *(const float4*)(Abase + (size_t)r * TK + k0 + c8 + 4);
    float4 a2 = *(const float4*)(Abase + (size_t)(r + 64) * TK + k0 + c8);
    float4 a3 = *(const float4*)(Abase + (size_t)(r + 64) * TK + k0 + c8 + 4);
    float4 f[4];
#pragma unroll
    for (int i = 0; i < 4; i++)
      f[i] = *(const float4*)(Ebase + (size_t)(k0 + kkB + i) * DIM + nnB);
    __syncthreads();
    *(f16x8*)&sA[r * LDSS + c8] = cvt8(a0, a1);
    *(f16x8*)&sA[(r + 64) * LDSS + c8] = cvt8(a2, a3);
#pragma unroll
    for (int c = 0; c < 4; c++) {
      f16x4 h;
      h[0] = (_Float16)((&f[0].x)[c]);
      h[1] = (_Float16)((&f[1].x)[c]);
      h[2] = (_Float16)((&f[2].x)[c]);
      h[3] = (_Float16)((&f[3].x)[c]);
      *(f16x4*)&sB[(nnB + c) * LDSS + kkB] = h;
    }
    __syncthreads();
    f16x8 aF[4], bF[4];
#pragma unroll
    for (int i = 0; i < 4; i++)
      aF[i] = *(const f16x8*)&sA[(wm * 64 + i * 16 + tm) * LDSS + quad * 8];
#pragma unroll
    for (int j = 0; j < 4; j++)
      bF[j] = *(const f16x8*)&sB[(wn * 64 + j * 16 + tm) * LDSS + quad * 8];
#pragma unroll
    for (int i = 0; i < 4; i++)
#pragma unroll
      for (int j = 0; j < 4; j++)
        acc[i][j] = __builtin_amdgcn_mfma_f32_16x16x32_f16(aF[i], bF[j], acc[i][j], 0, 0, 0);
  }
#pragma unroll
  for (int i = 0; i < 4; i++) {
#pragma unroll
    for (int rr = 0; rr < 4; rr++) {
      size_t rowoff = ((size_t)b * TQ + mt * BM + wm * 64 + i * 16 + quad * 4 + rr) * (size_t)DIM;
#pragma unroll
      for (int j = 0; j < 4; j++)
        C[rowoff + nt * BN + wn * 64 + j * 16 + tm] = acc[i][j][rr];
    }
  }
}

// ===========================================================================
extern "C" void kernel_launch(void* const* d_in, const int* in_sizes, int n_in,
                              void* d_out, int out_size, void* d_ws, size_t ws_size,
                              hipStream_t stream) {
  const float* dec = (const float*)d_in[0];
  const float* enc = (const float*)d_in[1];
  const int* mask = (const int*)d_in[2];

  float* ctx = (float*)d_out;               // [8, 2048, 1024]
  float* attn = (float*)d_out + CTX_ELEMS;  // [8, 2048, 2048]

  dim3 block(256);

  if (ws_size >= WS_NEEDED_BYTES) {
    _Float16* dec16 = (_Float16*)d_ws + WS_DEC;
    _Float16* enc16 = (_Float16*)d_ws + WS_ENC;
    _Float16* encT = (_Float16*)d_ws + WS_ENCT;
    _Float16* W16 = (_Float16*)d_ws + WS_W;

    convert_kernel<<<dim3(TK / 64, DIM / 64, BATCH), block, 0, stream>>>(
        enc, dec, enc16, encT, dec16);
    // grid: (b, nt, mt) — batch fastest for XCD-local L2 sharing
    gemm8p<TQ, TK, DIM><<<dim3(BATCH, TK / 256, TQ / 256), dim3(512), 0, stream>>>(dec16, enc16, attn);
    softmax_kernel<<<dim3(BATCH * TQ), block, 0, stream>>>(attn, mask, W16);
    gemm8p<TQ, DIM, TK><<<dim3(BATCH, DIM / 256, TQ / 256), dim3(512), 0, stream>>>(W16, encT, ctx);
  } else {
    score_kernel_fb<<<dim3(TK / BN, TQ / BM, BATCH), block, 0, stream>>>(dec, enc, attn);
    softmax_kernel<<<dim3(BATCH * TQ), block, 0, stream>>>(attn, mask, nullptr);
    ctx_kernel_fb<<<dim3(DIM / BN, TQ / BM, BATCH), block, 0, stream>>>(attn, enc, ctx);
  }
}